// Round 6
// baseline (308.786 us; speedup 1.0000x reference)
//
#include <hip/hip_runtime.h>
#include <cstdint>

constexpr int D = 256;     // D_IN == D_OUT
constexpr int TM = 64;     // block m-tile; block o-tile = 256 (full)

typedef __bf16 bf16x8 __attribute__((ext_vector_type(8)));
typedef float  f32x4  __attribute__((ext_vector_type(4)));

// ---- fused prep: one kernel, no atomics, one launch -------------------
// Block o (0..255) owns output row o of W2 = (C+I)W:
//   w[k] = W[o,k] + sum_{e: dst(e)==o} W[src(e),k];  b2[o] likewise.
// Then converts the row to frag-order bf16 hi/lo (same layout as before):
// per k-32 chunk kc: [o16b(16)][lane(64)][j(8)], B-frag lane holds
// B[o = o16b*16 + (lane&15)][k = kc*32 + (lane>>4)*8 + j]
__global__ void prep_fused(const float* __restrict__ W, const float* __restrict__ b,
                           const int* __restrict__ em, int E,
                           ushort* __restrict__ Wh, ushort* __restrict__ Wl,
                           float* __restrict__ b2) {
    __shared__ int sem[2048];                 // em pairs (E <= 1024)
    const int o = blockIdx.x;
    const int t = threadIdx.x;                // k index
    for (int i = t; i < 2 * E; i += 256) sem[i] = em[i];
    __syncthreads();

    float w = W[o * D + t];
    float bias = b[o];
    for (int e = 0; e < E; ++e) {             // uniform branch per block
        if (sem[e] == o) {
            int src = sem[E + e];
            w += W[src * D + t];
            bias += b[src];
        }
    }
    if (t == 0) b2[o] = bias;

    // split fp32 -> bf16 hi (truncate) + lo (RNE of exact residual)
    uint32_t u  = __float_as_uint(w);
    uint32_t hu = u & 0xFFFF0000u;
    float r = w - __uint_as_float(hu);
    uint32_t ru = __float_as_uint(r);
    uint32_t lu = ru + 0x7FFFu + ((ru >> 16) & 1u);
    int kc = t >> 5, kk = t & 31, q = kk >> 3, j = kk & 7;
    int o16b = o >> 4;
    int lane = (o & 15) + 16 * q;
    int idx = kc * 8192 + (o16b * 64 + lane) * 8 + j;
    Wh[idx] = (ushort)(hu >> 16);
    Wl[idx] = (ushort)(lu >> 16);
}

// ---- fp32x8 -> packed bf16 hi/lo uint4s (split, RNE on residual) ------
__device__ __forceinline__ void cvt8(const float4& f0, const float4& f1,
                                     uint4& hi, uint4& lo) {
    float xs[8] = {f0.x, f0.y, f0.z, f0.w, f1.x, f1.y, f1.z, f1.w};
    uint32_t h[8], l[8];
    #pragma unroll
    for (int j = 0; j < 8; ++j) {
        uint32_t u  = __float_as_uint(xs[j]);
        uint32_t hu = u & 0xFFFF0000u;
        h[j] = hu;
        float r = xs[j] - __uint_as_float(hu);
        uint32_t ru = __float_as_uint(r);
        l[j] = ru + 0x7FFFu + ((ru >> 16) & 1u);
    }
    hi = make_uint4((h[0] >> 16) | (h[1] & 0xFFFF0000u),
                    (h[2] >> 16) | (h[3] & 0xFFFF0000u),
                    (h[4] >> 16) | (h[5] & 0xFFFF0000u),
                    (h[6] >> 16) | (h[7] & 0xFFFF0000u));
    lo = make_uint4((l[0] >> 16) | (l[1] & 0xFFFF0000u),
                    (l[2] >> 16) | (l[3] & 0xFFFF0000u),
                    (l[4] >> 16) | (l[5] & 0xFFFF0000u),
                    (l[6] >> 16) | (l[7] & 0xFFFF0000u));
}

// ---- main: out[m,o] = (x[m,:].W2[o,:] + b2[o]) / bl[m] via split-bf16 MFMA
// block: 256 thr = 4 waves; tile m-64 x o-256; wave = m-64 x o-64 (acc 4x4).
// Latency attack this round:
//   - __launch_bounds__(256,4): 4 blocks/CU (VGPR<=128)
//   - X prefetch depth 2: chunk kc+2 issued at top of kc (regs ping-pong,
//     static indexing) -> issue-to-consume spans ~2 MFMA phases > HBM latency
//   - W: register double-buffer, 1 phase ahead (L2-resident, ~250cy)
//   - nontemporal out stores: streaming writes stop evicting X from L3
__global__ __launch_bounds__(256, 4) void resgcn_mfma(
    const float* __restrict__ X, const ushort* __restrict__ Whg,
    const ushort* __restrict__ Wlg, const float* __restrict__ b2,
    const float* __restrict__ blen, float* __restrict__ out, int M)
{
    __shared__ __align__(16) unsigned char smem[16384];
    ushort* XhP = (ushort*)smem;          // [2][4][64][8]  8 KB
    ushort* XlP = XhP + 4096;             // [2][4][64][8]  8 KB
    float*  E   = (float*)smem;           // epilogue slice [16][256] f32 16 KB

    const int tid  = threadIdx.x;
    const int lane = tid & 63;
    const int wv   = tid >> 6;                 // wave's o-quadrant
    const int m0   = blockIdx.x * TM;

    // X staging coords: thread covers row sm, 8-float quarter sh of each 32-k chunk
    const int sm = tid >> 2;                   // 0..63
    const int sh = tid & 3;                    // 0..3
    int srow = m0 + sm; if (srow >= M) srow = M - 1;   // clamp: real data, stores guarded
    const float* xrow = X + (size_t)srow * D + sh * 8;
    const int m16b = sm >> 4;
    const int wlane = (sm & 15) + 16 * sh;     // frag lane this thread fills

    // W frag base: idx = kc*8192 + ((wv*4+b)*64 + lane)*8
    const ushort* whb = Whg + ((wv * 4) * 64 + lane) * 8;
    const ushort* wlb = Wlg + ((wv * 4) * 64 + lane) * 8;

#define LOADW(BH, BL, c) do {                                             \
        _Pragma("unroll")                                                 \
        for (int b = 0; b < 4; ++b) {                                     \
            BH[b] = *(const bf16x8*)(whb + (c) * 8192 + b * 512);         \
            BL[b] = *(const bf16x8*)(wlb + (c) * 8192 + b * 512);         \
        } } while (0)

#define DOMFMA(BH, BL, cur) do {                                          \
        _Pragma("unroll")                                                 \
        for (int a = 0; a < 4; ++a) {                                     \
            bf16x8 ah = *(const bf16x8*)(XhP + (((cur)*4 + a)*64 + lane)*8); \
            bf16x8 al = *(const bf16x8*)(XlP + (((cur)*4 + a)*64 + lane)*8); \
            _Pragma("unroll")                                             \
            for (int b = 0; b < 4; ++b) {                                 \
                acc[a][b] = __builtin_amdgcn_mfma_f32_16x16x32_bf16(ah, BH[b], acc[a][b], 0, 0, 0); \
                acc[a][b] = __builtin_amdgcn_mfma_f32_16x16x32_bf16(al, BH[b], acc[a][b], 0, 0, 0); \
                acc[a][b] = __builtin_amdgcn_mfma_f32_16x16x32_bf16(ah, BL[b], acc[a][b], 0, 0, 0); \
            } } } while (0)

#define STAGEX(nf0, nf1, buf) do {                                        \
        uint4 h_, l_;                                                     \
        cvt8(nf0, nf1, h_, l_);                                           \
        *(uint4*)(XhP + (((buf)*4 + m16b)*64 + wlane)*8) = h_;            \
        *(uint4*)(XlP + (((buf)*4 + m16b)*64 + wlane)*8) = l_;            \
    } while (0)

    f32x4 acc[4][4];
    #pragma unroll
    for (int a = 0; a < 4; ++a)
        #pragma unroll
        for (int b = 0; b < 4; ++b) acc[a][b] = (f32x4){0.f, 0.f, 0.f, 0.f};

    bf16x8 bhA[4], blA[4], bhB[4], blB[4];
    float4 xA0, xA1, xB0, xB1;

    LOADW(bhA, blA, 0);
    // prologue: stage chunk 0 now; issue chunk 1 into xA (consumed next phase)
    {
        float4 f0 = *(const float4*)(xrow + 0);
        float4 f1 = *(const float4*)(xrow + 4);
        STAGEX(f0, f1, 0);
    }
    xA0 = *(const float4*)(xrow + 32);
    xA1 = *(const float4*)(xrow + 36);
    __syncthreads();

    #pragma unroll
    for (int kc = 0; kc < 8; kc += 2) {
        // even phase: consume W-A(kc)+buf0; stage xA(=kc+1)->buf1;
        //             issue xB = X(kc+2); prefetch W-B(kc+1)
        {
            if (kc + 2 < 8) {
                const float* p = xrow + (kc + 2) * 32;
                xB0 = *(const float4*)(p + 0);
                xB1 = *(const float4*)(p + 4);
            }
            LOADW(bhB, blB, kc + 1);
            DOMFMA(bhA, blA, 0);
            STAGEX(xA0, xA1, 1);
            __syncthreads();
        }
        // odd phase: consume W-B(kc+1)+buf1; stage xB(=kc+2)->buf0;
        //            issue xA = X(kc+3); prefetch W-A(kc+2)
        {
            if (kc + 3 < 8) {
                const float* p = xrow + (kc + 3) * 32;
                xA0 = *(const float4*)(p + 0);
                xA1 = *(const float4*)(p + 4);
            }
            if (kc + 2 < 8) LOADW(bhA, blA, kc + 2);
            DOMFMA(bhB, blB, 1);
            if (kc + 2 < 8) STAGEX(xB0, xB1, 0);
            __syncthreads();
        }
    }
    // loop-end barrier: all X ds_reads complete -> smem reusable as E

    // ---- epilogue: LDS-transposed float4 nontemporal stores -------------
    // C/D layout col=lane&15, row=(lane>>4)*4+reg  (m89-verified)
    const int col = lane & 15;
    const int rq  = lane >> 4;
    float bias[4];
    #pragma unroll
    for (int b = 0; b < 4; ++b) bias[b] = b2[(wv * 4 + b) * 16 + col];

    #pragma unroll
    for (int a = 0; a < 4; ++a) {
        if (a) __syncthreads();            // protect E reuse across slices
        #pragma unroll
        for (int r = 0; r < 4; ++r) {
            int row = rq * 4 + r;
            int sw  = (row & 7) << 2;
            #pragma unroll
            for (int b = 0; b < 4; ++b) {
                int o = wv * 64 + b * 16 + col;
                E[row * 256 + (o ^ sw)] = acc[a][b][r] + bias[b];
            }
        }
        __syncthreads();
        #pragma unroll
        for (int j = 0; j < 4; ++j) {
            int row = wv * 4 + j;
            int m = m0 + a * 16 + row;
            f32x4 v = *(const f32x4*)&E[row * 256 + ((lane ^ (row & 7)) << 2)];
            if (m < M) {
                float inv = 1.0f / blen[m];
                f32x4 o4 = {v[0] * inv, v[1] * inv, v[2] * inv, v[3] * inv};
                __builtin_nontemporal_store(o4, (f32x4*)&out[(size_t)m * D + lane * 4]);
            }
        }
    }
#undef LOADW
#undef DOMFMA
#undef STAGEX
}

extern "C" void kernel_launch(void* const* d_in, const int* in_sizes, int n_in,
                              void* d_out, int out_size, void* d_ws, size_t ws_size,
                              hipStream_t stream) {
    (void)n_in; (void)out_size; (void)ws_size;
    const float* X  = (const float*)d_in[0];
    const float* W  = (const float*)d_in[1];
    const float* b  = (const float*)d_in[2];
    const int*   em = (const int*)d_in[3];
    const float* bl = (const float*)d_in[4];
    float* out = (float*)d_out;

    const int M = in_sizes[0] / D;
    const int E = in_sizes[3] / 2;

    float*  b2 = (float*)d_ws;            // 256 fp32 (1 KB)
    ushort* Wh = (ushort*)(b2 + D);       // 65536 bf16
    ushort* Wl = Wh + D * D;              // 65536 bf16

    prep_fused<<<D, 256, 0, stream>>>(W, b, em, E, Wh, Wl, b2);

    int mblocks = (M + TM - 1) / TM;
    resgcn_mfma<<<mblocks, 256, 0, stream>>>(X, Wh, Wl, b2, bl, out, M);
}

// Round 7
// 304.742 us; speedup vs baseline: 1.0133x; 1.0133x over previous
//
#include <hip/hip_runtime.h>
#include <cstdint>

constexpr int D = 256;     // D_IN == D_OUT
constexpr int TM = 64;     // block m-tile; block o-tile = 256 (full)

typedef __bf16 bf16x8 __attribute__((ext_vector_type(8)));
typedef float  f32x4  __attribute__((ext_vector_type(4)));

// ---- fused prep: one kernel, no atomics, one launch -------------------
// Block o (0..255) owns output row o of W2 = (C+I)W:
//   w[k] = W[o,k] + sum_{e: dst(e)==o} W[src(e),k];  b2[o] likewise.
// Then converts the row to frag-order bf16 hi/lo:
// per k-32 chunk kc: [o16b(16)][lane(64)][j(8)], B-frag lane holds
// B[o = o16b*16 + (lane&15)][k = kc*32 + (lane>>4)*8 + j]
__global__ void prep_fused(const float* __restrict__ W, const float* __restrict__ b,
                           const int* __restrict__ em, int E,
                           ushort* __restrict__ Wh, ushort* __restrict__ Wl,
                           float* __restrict__ b2) {
    __shared__ int sem[2048];                 // em pairs (E <= 1024)
    const int o = blockIdx.x;
    const int t = threadIdx.x;                // k index
    for (int i = t; i < 2 * E; i += 256) sem[i] = em[i];
    __syncthreads();

    float w = W[o * D + t];
    float bias = b[o];
    for (int e = 0; e < E; ++e) {             // uniform branch per block
        if (sem[e] == o) {
            int src = sem[E + e];
            w += W[src * D + t];
            bias += b[src];
        }
    }
    if (t == 0) b2[o] = bias;

    // split fp32 -> bf16 hi (truncate) + lo (RNE of exact residual)
    uint32_t u  = __float_as_uint(w);
    uint32_t hu = u & 0xFFFF0000u;
    float r = w - __uint_as_float(hu);
    uint32_t ru = __float_as_uint(r);
    uint32_t lu = ru + 0x7FFFu + ((ru >> 16) & 1u);
    int kc = t >> 5, kk = t & 31, q = kk >> 3, j = kk & 7;
    int o16b = o >> 4;
    int lane = (o & 15) + 16 * q;
    int idx = kc * 8192 + (o16b * 64 + lane) * 8 + j;
    Wh[idx] = (ushort)(hu >> 16);
    Wl[idx] = (ushort)(lu >> 16);
}

// ---- fp32x8 -> packed bf16 hi/lo uint4s (split, RNE on residual) ------
__device__ __forceinline__ void cvt8(const float4& f0, const float4& f1,
                                     uint4& hi, uint4& lo) {
    float xs[8] = {f0.x, f0.y, f0.z, f0.w, f1.x, f1.y, f1.z, f1.w};
    uint32_t h[8], l[8];
    #pragma unroll
    for (int j = 0; j < 8; ++j) {
        uint32_t u  = __float_as_uint(xs[j]);
        uint32_t hu = u & 0xFFFF0000u;
        h[j] = hu;
        float r = xs[j] - __uint_as_float(hu);
        uint32_t ru = __float_as_uint(r);
        l[j] = ru + 0x7FFFu + ((ru >> 16) & 1u);
    }
    hi = make_uint4((h[0] >> 16) | (h[1] & 0xFFFF0000u),
                    (h[2] >> 16) | (h[3] & 0xFFFF0000u),
                    (h[4] >> 16) | (h[5] & 0xFFFF0000u),
                    (h[6] >> 16) | (h[7] & 0xFFFF0000u));
    lo = make_uint4((l[0] >> 16) | (l[1] & 0xFFFF0000u),
                    (l[2] >> 16) | (l[3] & 0xFFFF0000u),
                    (l[4] >> 16) | (l[5] & 0xFFFF0000u),
                    (l[6] >> 16) | (l[7] & 0xFFFF0000u));
}

// ---- main: out[m,o] = (x[m,:].W2[o,:] + b2[o]) / bl[m] via split-bf16 MFMA
// block: 256 thr = 4 waves; tile m-64 x o-256; wave = m-64 x o-64 (acc 4x4).
//   - __launch_bounds__(256,4): 4 blocks/CU (VGPR 64, 33% occupancy measured)
//   - X prefetch depth 2 (regs ping-pong, static indexing)
//   - W: register double-buffer, 1 phase ahead (L2-resident)
//   - epilogue: LDS-transpose -> row-dense PLAIN float4 stores.
//     (R6 lesson: nontemporal `nt` stores bypass L2 write-merging ->
//      WRITE_SIZE 100->181 MB, FETCH +28 MB, +47us. Never nt small stores.)
__global__ __launch_bounds__(256, 4) void resgcn_mfma(
    const float* __restrict__ X, const ushort* __restrict__ Whg,
    const ushort* __restrict__ Wlg, const float* __restrict__ b2,
    const float* __restrict__ blen, float* __restrict__ out, int M)
{
    __shared__ __align__(16) unsigned char smem[16384];
    ushort* XhP = (ushort*)smem;          // [2][4][64][8]  8 KB
    ushort* XlP = XhP + 4096;             // [2][4][64][8]  8 KB
    float*  E   = (float*)smem;           // epilogue slice [16][256] f32 16 KB

    const int tid  = threadIdx.x;
    const int lane = tid & 63;
    const int wv   = tid >> 6;                 // wave's o-quadrant
    const int m0   = blockIdx.x * TM;

    // X staging coords: thread covers row sm, 8-float quarter sh of each 32-k chunk
    const int sm = tid >> 2;                   // 0..63
    const int sh = tid & 3;                    // 0..3
    int srow = m0 + sm; if (srow >= M) srow = M - 1;   // clamp: real data, stores guarded
    const float* xrow = X + (size_t)srow * D + sh * 8;
    const int m16b = sm >> 4;
    const int wlane = (sm & 15) + 16 * sh;     // frag lane this thread fills

    // W frag base: idx = kc*8192 + ((wv*4+b)*64 + lane)*8
    const ushort* whb = Whg + ((wv * 4) * 64 + lane) * 8;
    const ushort* wlb = Wlg + ((wv * 4) * 64 + lane) * 8;

#define LOADW(BH, BL, c) do {                                             \
        _Pragma("unroll")                                                 \
        for (int b = 0; b < 4; ++b) {                                     \
            BH[b] = *(const bf16x8*)(whb + (c) * 8192 + b * 512);         \
            BL[b] = *(const bf16x8*)(wlb + (c) * 8192 + b * 512);         \
        } } while (0)

#define DOMFMA(BH, BL, cur) do {                                          \
        _Pragma("unroll")                                                 \
        for (int a = 0; a < 4; ++a) {                                     \
            bf16x8 ah = *(const bf16x8*)(XhP + (((cur)*4 + a)*64 + lane)*8); \
            bf16x8 al = *(const bf16x8*)(XlP + (((cur)*4 + a)*64 + lane)*8); \
            _Pragma("unroll")                                             \
            for (int b = 0; b < 4; ++b) {                                 \
                acc[a][b] = __builtin_amdgcn_mfma_f32_16x16x32_bf16(ah, BH[b], acc[a][b], 0, 0, 0); \
                acc[a][b] = __builtin_amdgcn_mfma_f32_16x16x32_bf16(al, BH[b], acc[a][b], 0, 0, 0); \
                acc[a][b] = __builtin_amdgcn_mfma_f32_16x16x32_bf16(ah, BL[b], acc[a][b], 0, 0, 0); \
            } } } while (0)

#define STAGEX(nf0, nf1, buf) do {                                        \
        uint4 h_, l_;                                                     \
        cvt8(nf0, nf1, h_, l_);                                           \
        *(uint4*)(XhP + (((buf)*4 + m16b)*64 + wlane)*8) = h_;            \
        *(uint4*)(XlP + (((buf)*4 + m16b)*64 + wlane)*8) = l_;            \
    } while (0)

    f32x4 acc[4][4];
    #pragma unroll
    for (int a = 0; a < 4; ++a)
        #pragma unroll
        for (int b = 0; b < 4; ++b) acc[a][b] = (f32x4){0.f, 0.f, 0.f, 0.f};

    bf16x8 bhA[4], blA[4], bhB[4], blB[4];
    float4 xA0, xA1, xB0, xB1;

    LOADW(bhA, blA, 0);
    // prologue: stage chunk 0 now; issue chunk 1 into xA (consumed next phase)
    {
        float4 f0 = *(const float4*)(xrow + 0);
        float4 f1 = *(const float4*)(xrow + 4);
        STAGEX(f0, f1, 0);
    }
    xA0 = *(const float4*)(xrow + 32);
    xA1 = *(const float4*)(xrow + 36);
    __syncthreads();

    #pragma unroll
    for (int kc = 0; kc < 8; kc += 2) {
        // even phase: consume W-A(kc)+buf0; stage xA(=kc+1)->buf1;
        //             issue xB = X(kc+2); prefetch W-B(kc+1)
        {
            if (kc + 2 < 8) {
                const float* p = xrow + (kc + 2) * 32;
                xB0 = *(const float4*)(p + 0);
                xB1 = *(const float4*)(p + 4);
            }
            LOADW(bhB, blB, kc + 1);
            DOMFMA(bhA, blA, 0);
            STAGEX(xA0, xA1, 1);
            __syncthreads();
        }
        // odd phase: consume W-B(kc+1)+buf1; stage xB(=kc+2)->buf0;
        //            issue xA = X(kc+3); prefetch W-A(kc+2)
        {
            if (kc + 3 < 8) {
                const float* p = xrow + (kc + 3) * 32;
                xA0 = *(const float4*)(p + 0);
                xA1 = *(const float4*)(p + 4);
            }
            if (kc + 2 < 8) LOADW(bhA, blA, kc + 2);
            DOMFMA(bhB, blB, 1);
            if (kc + 2 < 8) STAGEX(xB0, xB1, 0);
            __syncthreads();
        }
    }
    // loop-end barrier: all X ds_reads complete -> smem reusable as E

    // ---- epilogue: LDS-transposed float4 stores --------------------------
    // C/D layout col=lane&15, row=(lane>>4)*4+reg  (m89-verified)
    const int col = lane & 15;
    const int rq  = lane >> 4;
    float bias[4];
    #pragma unroll
    for (int b = 0; b < 4; ++b) bias[b] = b2[(wv * 4 + b) * 16 + col];

    #pragma unroll
    for (int a = 0; a < 4; ++a) {
        if (a) __syncthreads();            // protect E reuse across slices
        #pragma unroll
        for (int r = 0; r < 4; ++r) {
            int row = rq * 4 + r;
            int sw  = (row & 7) << 2;
            #pragma unroll
            for (int b = 0; b < 4; ++b) {
                int o = wv * 64 + b * 16 + col;
                E[row * 256 + (o ^ sw)] = acc[a][b][r] + bias[b];
            }
        }
        __syncthreads();
        #pragma unroll
        for (int j = 0; j < 4; ++j) {
            int row = wv * 4 + j;
            int m = m0 + a * 16 + row;
            f32x4 v = *(const f32x4*)&E[row * 256 + ((lane ^ (row & 7)) << 2)];
            if (m < M) {
                float inv = 1.0f / blen[m];
                f32x4 o4 = {v[0] * inv, v[1] * inv, v[2] * inv, v[3] * inv};
                *(f32x4*)&out[(size_t)m * D + lane * 4] = o4;
            }
        }
    }
#undef LOADW
#undef DOMFMA
#undef STAGEX
}

extern "C" void kernel_launch(void* const* d_in, const int* in_sizes, int n_in,
                              void* d_out, int out_size, void* d_ws, size_t ws_size,
                              hipStream_t stream) {
    (void)n_in; (void)out_size; (void)ws_size;
    const float* X  = (const float*)d_in[0];
    const float* W  = (const float*)d_in[1];
    const float* b  = (const float*)d_in[2];
    const int*   em = (const int*)d_in[3];
    const float* bl = (const float*)d_in[4];
    float* out = (float*)d_out;

    const int M = in_sizes[0] / D;
    const int E = in_sizes[3] / 2;

    float*  b2 = (float*)d_ws;            // 256 fp32 (1 KB)
    ushort* Wh = (ushort*)(b2 + D);       // 65536 bf16
    ushort* Wl = Wh + D * D;              // 65536 bf16

    prep_fused<<<D, 256, 0, stream>>>(W, b, em, E, Wh, Wl, b2);

    int mblocks = (M + TM - 1) / TM;
    resgcn_mfma<<<mblocks, 256, 0, stream>>>(X, Wh, Wl, b2, bl, out, M);
}